// Round 24
// baseline (53.005 us; speedup 1.0000x reference)
//
#include <hip/hip_runtime.h>
#include <math.h>

#define Bq 64
#define Tq 1024
#define Nq 128
#define SEG 129              // segments per chain (R22-proven)
#define NFW (SEG - 1)        // 128 forward workers: s = 1..128
#define NBW (SEG - 1)        // 128 backward workers: s = 2..129
#define WPC 16               // worker waves per chain (8 fwd + 8 bwd)
#define LN2 0.6931471805599453f

typedef __attribute__((ext_vector_type(8))) _Float16 half8;
typedef __attribute__((ext_vector_type(2))) _Float16 h2;
typedef __attribute__((ext_vector_type(4))) float f32x4;

union BU { int u[4]; int4 v; half8 h; };
union E8 { int2 v; h2 p[2]; };          // 4 f16
union E16 { int2 v2[2]; half8 h; };     // 8 f16 as two int2 loads

__device__ __forceinline__ int pk16(float a, float b) {
    auto p = __builtin_amdgcn_cvt_pkrtz(a, b);
    return *(int*)&p;
}

// Permuted m-slot map (R20-proven): k-slot (call q, lane-group g, word j) holds
//   m = 16*(2q + (j>>2)) + 4g + (j&3)  == D-slot (same lane, acc[2q+(j>>2)], reg j&3)
__device__ __forceinline__ int MMAP(int q, int g, int j) {
    return 16 * (2 * q + (j >> 2)) + 4 * g + (j & 3);
}

// ---------------------------------------------------------------------------
// Prep: blocks 0..4095   : eeh = (f16) exp(emissions), skipping rows >= tsz
//       blocks 4096..4111: pack exp(transitions) into PERMUTED fragment layout
// ---------------------------------------------------------------------------
__global__ __launch_bounds__(256)
void crf_prep_kernel(const float* __restrict__ em,
                     const float* __restrict__ trans,
                     const int* __restrict__ token_sizes,
                     _Float16* __restrict__ eeh,
                     int4* __restrict__ aF, int4* __restrict__ aB) {
    const int bid = blockIdx.x;
    const int tid = threadIdx.x;
    if (bid < 4096) {
        // each block covers 2048 contiguous elements = 16 rows of one chain
        const int b = bid >> 6;
        const int row0 = (bid & 63) * 16;
        if (row0 >= token_sizes[b]) return;   // rows never read by workers
        const size_t i = ((size_t)bid * 256 + tid) * 8;
        const float4* src = (const float4*)(em + i);
        float4 x0 = src[0], x1 = src[1];
        BU r;
        r.u[0] = pk16(__expf(x0.x), __expf(x0.y));
        r.u[1] = pk16(__expf(x0.z), __expf(x0.w));
        r.u[2] = pk16(__expf(x1.x), __expf(x1.y));
        r.u[3] = pk16(__expf(x1.z), __expf(x1.w));
        *(int4*)(eeh + i) = r.v;
        return;
    }
    {
        const int fb = bid - 4096;            // 0..7 aF, 8..15 aB
        const bool fwd = (fb < 8);
        const int kf = (fb & 7) * 4 + (tid >> 6);   // fragment 0..31
        const int L = tid & 63;
        const int c = L & 15, g = L >> 4;
        const int r = kf >> 2, q = kf & 3;
        BU v;
        #pragma unroll
        for (int j = 0; j < 8; ++j) {
            const int m = MMAP(q, g, j);
            const int n = 16 * r + c;
            const float tv = fwd ? trans[m * Nq + n] : trans[n * Nq + m];
            v.h[j] = (_Float16)__expf(tv);
        }
        (fwd ? aF : aB)[kf * 64 + L] = v.v;
    }
}

// ---------------------------------------------------------------------------
// FWD step — R20/R22-proven body (lane-local relayout, f16 ee from eeh).
// ---------------------------------------------------------------------------
__device__ __forceinline__ void fwd_step(
    int k, int lenc, int lo, int hi, int g,
    const _Float16* __restrict__ eeh_c,
    const half8 (&afrag)[32], BU (&bf)[4],
    E8 (&eeCur)[8], E8 (&eeNxt)[8], int& Ecum)
{
    f32x4 acc[8];
    #pragma unroll
    for (int r = 0; r < 8; ++r) {
        f32x4 z = {0.f, 0.f, 0.f, 0.f};
        z = __builtin_amdgcn_mfma_f32_16x16x32_f16(afrag[r*4+0], bf[0].h, z, 0, 0, 0);
        z = __builtin_amdgcn_mfma_f32_16x16x32_f16(afrag[r*4+1], bf[1].h, z, 0, 0, 0);
        z = __builtin_amdgcn_mfma_f32_16x16x32_f16(afrag[r*4+2], bf[2].h, z, 0, 0, 0);
        z = __builtin_amdgcn_mfma_f32_16x16x32_f16(afrag[r*4+3], bf[3].h, z, 0, 0, 0);
        acc[r] = z;
    }
    {   // prefetch next step's ee row (D layout: 8 x 8B per lane)
        const int tn = min(lo + k, hi);
        const _Float16* bp = eeh_c + (size_t)tn * Nq;
        #pragma unroll
        for (int r = 0; r < 8; ++r)
            eeNxt[r].v = *(const int2*)(bp + 16*r + 4*g);
    }
    float w[32];
    float mx = 0.f;
    #pragma unroll
    for (int r = 0; r < 8; ++r) {
        #pragma unroll
        for (int i = 0; i < 4; ++i) {
            const float ee = (float)eeCur[r].p[i >> 1][i & 1];
            const float wv = acc[r][i] * ee;
            w[r*4+i] = wv;
            mx = fmaxf(mx, wv);
        }
    }
    mx = fmaxf(mx, __shfl_xor(mx, 16, 64));
    mx = fmaxf(mx, __shfl_xor(mx, 32, 64));
    const int eb = (__float_as_int(mx) >> 23) & 255;
    const float sig = __int_as_float((253 - eb) << 23);
    const bool act = (k <= lenc);
    #pragma unroll
    for (int q = 0; q < 4; ++q) {   // D -> B: lane-local (permuted-E layout)
        const int n0 = pk16(w[8*q+0]*sig, w[8*q+1]*sig);
        const int n1 = pk16(w[8*q+2]*sig, w[8*q+3]*sig);
        const int n2 = pk16(w[8*q+4]*sig, w[8*q+5]*sig);
        const int n3 = pk16(w[8*q+6]*sig, w[8*q+7]*sig);
        bf[q].u[0] = act ? n0 : bf[q].u[0];
        bf[q].u[1] = act ? n1 : bf[q].u[1];
        bf[q].u[2] = act ? n2 : bf[q].u[2];
        bf[q].u[3] = act ? n3 : bf[q].u[3];
    }
    Ecum += act ? (eb - 126) : 0;
}

// ---------------------------------------------------------------------------
// BWD step — R20/R22-proven body (ee pk_mul on B operand; lane-local relayout).
// ---------------------------------------------------------------------------
__device__ __forceinline__ void bwd_step(
    int k, int lenc, int lo, int hi, int g,
    const _Float16* __restrict__ eeh_c,
    const half8 (&afrag)[32], BU (&bf)[4],
    E16 (&eeCur)[4], E16 (&eeNxt)[4], int& Ecum)
{
    BU beff[4];
    #pragma unroll
    for (int q = 0; q < 4; ++q) beff[q].h = bf[q].h * eeCur[q].h;  // v_pk_mul_f16
    f32x4 acc[8];
    #pragma unroll
    for (int r = 0; r < 8; ++r) {
        f32x4 z = {0.f, 0.f, 0.f, 0.f};
        z = __builtin_amdgcn_mfma_f32_16x16x32_f16(afrag[r*4+0], beff[0].h, z, 0, 0, 0);
        z = __builtin_amdgcn_mfma_f32_16x16x32_f16(afrag[r*4+1], beff[1].h, z, 0, 0, 0);
        z = __builtin_amdgcn_mfma_f32_16x16x32_f16(afrag[r*4+2], beff[2].h, z, 0, 0, 0);
        z = __builtin_amdgcn_mfma_f32_16x16x32_f16(afrag[r*4+3], beff[3].h, z, 0, 0, 0);
        acc[r] = z;
    }
    {   // prefetch next step's ee row (permuted B layout: 2 int2 per q)
        const int tn = max(hi - k, lo);
        const _Float16* bp = eeh_c + (size_t)tn * Nq;
        #pragma unroll
        for (int q = 0; q < 4; ++q) {
            eeNxt[q].v2[0] = *(const int2*)(bp + 32*q + 4*g);
            eeNxt[q].v2[1] = *(const int2*)(bp + 32*q + 16 + 4*g);
        }
    }
    float mx = 0.f;
    #pragma unroll
    for (int r = 0; r < 8; ++r) {
        #pragma unroll
        for (int i = 0; i < 4; ++i) mx = fmaxf(mx, acc[r][i]);
    }
    mx = fmaxf(mx, __shfl_xor(mx, 16, 64));
    mx = fmaxf(mx, __shfl_xor(mx, 32, 64));
    const int eb = (__float_as_int(mx) >> 23) & 255;
    const float sig = __int_as_float((253 - eb) << 23);
    const bool act = (k <= lenc);
    #pragma unroll
    for (int q = 0; q < 4; ++q) {
        const int n0 = pk16(acc[2*q][0]*sig,   acc[2*q][1]*sig);
        const int n1 = pk16(acc[2*q][2]*sig,   acc[2*q][3]*sig);
        const int n2 = pk16(acc[2*q+1][0]*sig, acc[2*q+1][1]*sig);
        const int n3 = pk16(acc[2*q+1][2]*sig, acc[2*q+1][3]*sig);
        bf[q].u[0] = act ? n0 : bf[q].u[0];
        bf[q].u[1] = act ? n1 : bf[q].u[1];
        bf[q].u[2] = act ? n2 : bf[q].u[2];
        bf[q].u[3] = act ? n3 : bf[q].u[3];
    }
    Ecum += act ? (eb - 126) : 0;
}

// ---------------------------------------------------------------------------
// Blocks 0..1023: worker waves. bid: chain b=bid>>4, wv=bid&15 (0..7 fwd, 8..15 bwd).
// Blocks 1024..1087: gold-path score for chain (bid-1024); also zeroes out[b].
// Worker vectors stored f32 in natural state order (R22-proven format).
// ---------------------------------------------------------------------------
__global__ __launch_bounds__(64, 1)
void crf_worker_kernel(const float* __restrict__ emissions,
                       const _Float16* __restrict__ eeh,
                       const int4* __restrict__ aF,
                       const int4* __restrict__ aB,
                       const int* __restrict__ token_sizes,
                       const int* __restrict__ targets,
                       const float* __restrict__ transitions,
                       const float* __restrict__ head,
                       const float* __restrict__ last,
                       float* __restrict__ wsA, float* __restrict__ wsB,
                       float* __restrict__ wsLa, float* __restrict__ wsLb,
                       float* __restrict__ out) {
    const int L = threadIdx.x;
    const int bid = blockIdx.x;

    if (bid >= Bq * WPC) {
        // ---------------- score path (one wave per chain) ----------------
        const int b = bid - Bq * WPC;
        const int tsz = token_sizes[b];
        const int* tg = targets + b * Tq;
        const float* emc = emissions + (size_t)b * Tq * Nq;
        float sc = 0.f;
        for (int t = L; t < tsz; t += 64) {
            int cur = tg[t];
            sc += emc[(size_t)t * Nq + cur];
            if (t >= 1) sc += transitions[tg[t - 1] * Nq + cur];
        }
        #pragma unroll
        for (int off = 32; off >= 1; off >>= 1)
            sc += __shfl_xor(sc, off, 64);
        if (L == 0) {
            out[Bq + b] = sc + head[tg[0]] + last[tg[tsz - 1]];
            out[b] = 0.0f;                 // zero logZ slot for combine atomics
        }
        return;
    }

    const int b = bid >> 4;
    const int wv = bid & 15;
    const bool isFwd = (wv < 8);
    const int half_ = wv & 7;
    const int c = L & 15;
    const int g = L >> 4;
    const int s = (isFwd ? 1 : 2) + 16 * half_ + c;

    const float* em_c = emissions + (size_t)b * Tq * Nq;
    const _Float16* eeh_c = eeh + (size_t)b * Tq * Nq;
    const int tsz = token_sizes[b];
    const int nst = tsz - 1;
    const int base = nst / SEG;              // >= 3
    const int rem = nst % SEG;
    const int lo = 1 + (s - 1) * base + min(s - 1, rem);
    const int lenc = base + ((s <= rem) ? 1 : 0);
    const int hi = lo + lenc - 1;
    const int kmax = base + 1;

    // A fragments: 32 coalesced b128 loads (permuted layout from prep)
    half8 afrag[32];
    {
        const int4* asrc = isFwd ? aF : aB;
        #pragma unroll
        for (int kf = 0; kf < 32; ++kf) {
            BU t; t.v = asrc[kf * 64 + L];
            afrag[kf] = t.h;
        }
    }

    // init vector in PERMUTED B layout
    BU bf[4];
    float M0c;
    {
        float a0[32];
        float mx = -1e30f;
        #pragma unroll
        for (int q = 0; q < 4; ++q) {
            #pragma unroll
            for (int j2 = 0; j2 < 8; ++j2) {
                const int m = MMAP(q, g, j2);
                float v;
                if (isFwd) v = (s == 1)   ? (head[m] + em_c[m]) : 0.f;
                else       v = (s == SEG) ? last[m]             : 0.f;
                a0[q*8+j2] = v;
                mx = fmaxf(mx, v);
            }
        }
        mx = fmaxf(mx, __shfl_xor(mx, 16, 64));
        mx = fmaxf(mx, __shfl_xor(mx, 32, 64));
        M0c = mx;
        #pragma unroll
        for (int q = 0; q < 4; ++q) {
            #pragma unroll
            for (int p = 0; p < 4; ++p)
                bf[q].u[p] = pk16(__expf(a0[q*8+2*p]   - M0c),
                                  __expf(a0[q*8+2*p+1] - M0c));
        }
    }

    int Ecum = 0;
    int k = 1;
    if (isFwd) {
        E8 eeA[8], eeB8[8];
        const _Float16* bp = eeh_c + (size_t)lo * Nq;
        #pragma unroll
        for (int r = 0; r < 8; ++r) eeA[r].v = *(const int2*)(bp + 16*r + 4*g);
        for (; k + 1 <= kmax; k += 2) {
            fwd_step(k,   lenc, lo, hi, g, eeh_c, afrag, bf, eeA, eeB8, Ecum);
            fwd_step(k+1, lenc, lo, hi, g, eeh_c, afrag, bf, eeB8, eeA, Ecum);
        }
        if (k <= kmax)
            fwd_step(k, lenc, lo, hi, g, eeh_c, afrag, bf, eeA, eeB8, Ecum);
    } else {
        E16 eeA[4], eeB8[4];
        const _Float16* bp = eeh_c + (size_t)hi * Nq;
        #pragma unroll
        for (int q = 0; q < 4; ++q) {
            eeA[q].v2[0] = *(const int2*)(bp + 32*q + 4*g);
            eeA[q].v2[1] = *(const int2*)(bp + 32*q + 16 + 4*g);
        }
        for (; k + 1 <= kmax; k += 2) {
            bwd_step(k,   lenc, lo, hi, g, eeh_c, afrag, bf, eeA, eeB8, Ecum);
            bwd_step(k+1, lenc, lo, hi, g, eeh_c, afrag, bf, eeB8, eeA, Ecum);
        }
        if (k <= kmax)
            bwd_step(k, lenc, lo, hi, g, eeh_c, afrag, bf, eeA, eeB8, Ecum);
    }

    // store vector (two contiguous float4 per call, natural state order) + ledger
    {
        float* dst = isFwd ? (wsA + ((size_t)(s - 1) * Bq + b) * Nq)
                           : (wsB + ((size_t)(s - 2) * Bq + b) * Nq);
        #pragma unroll
        for (int q = 0; q < 4; ++q) {
            f32x4 v0, v1;
            #pragma unroll
            for (int t = 0; t < 4; ++t) { v0[t] = (float)bf[q].h[t]; v1[t] = (float)bf[q].h[4+t]; }
            *(f32x4*)(dst + 32*q + 4*g)      = v0;
            *(f32x4*)(dst + 32*q + 16 + 4*g) = v1;
        }
        if (g == 0) {
            const float led = M0c + (float)Ecum * LN2;
            if (isFwd) wsLa[(s - 1) * Bq + b] = led;
            else       wsLb[(s - 2) * Bq + b] = led;
        }
    }
}

// ---------------------------------------------------------------------------
// Combine (rank-1 telescope, R22-proven junction math): 256 blocks
// (4 per chain x 8 waves = 32 waves/chain), each wave handles 4 of the 128
// junctions; per-wave partials atomicAdd into out[chain] (pre-zeroed).
//   j in 0..126 (s=j+2): term = log(B[j].A[j]) + La[j] - log(sum B[j])
//   j == 127 (top)     : term = log(B[127].A[127]) + La[127] + Lb[127]
// ---------------------------------------------------------------------------
__global__ __launch_bounds__(512)
void crf_combine_kernel(const float* __restrict__ wsA,
                        const float* __restrict__ wsB,
                        const float* __restrict__ wsLa,
                        const float* __restrict__ wsLb,
                        float* __restrict__ out) {
    const int chain = blockIdx.x >> 2;
    const int sub = blockIdx.x & 3;
    const int wq = sub * 8 + (threadIdx.x >> 6);   // wave index 0..31
    const int l = threadIdx.x & 63;

    float tot = 0.f;
    #pragma unroll
    for (int rep = 0; rep < 4; ++rep) {            // j = wq + 32*rep, 128 total
        const int j = wq + 32 * rep;
        const float* bb = wsB + ((size_t)j * Bq + chain) * Nq;
        const float* aa = wsA + ((size_t)j * Bq + chain) * Nq;
        float z = bb[l] * aa[l] + bb[l + 64] * aa[l + 64];
        float cc = bb[l] + bb[l + 64];
        #pragma unroll
        for (int off = 32; off >= 1; off >>= 1) {
            z  += __shfl_xor(z, off, 64);
            cc += __shfl_xor(cc, off, 64);
        }
        float term = __logf(z) + wsLa[j * Bq + chain];
        term += (j == NFW - 1) ? wsLb[(NBW - 1) * Bq + chain] : -__logf(cc);
        tot += term;
    }
    if (l == 0) atomicAdd(&out[chain], tot);
}

extern "C" void kernel_launch(void* const* d_in, const int* in_sizes, int n_in,
                              void* d_out, int out_size, void* d_ws, size_t ws_size,
                              hipStream_t stream) {
    const float* emissions   = (const float*)d_in[0];
    const int*   token_sizes = (const int*)d_in[1];
    const int*   targets     = (const int*)d_in[2];
    const float* transitions = (const float*)d_in[3];  // (1,1,128,128)
    const float* head        = (const float*)d_in[4];  // (1,1,128)
    const float* last        = (const float*)d_in[5];  // (1,1,128)
    float* out = (float*)d_out;                        // (2,64,1) flat

    char* wp = (char*)d_ws;
    _Float16* eeh = (_Float16*)wp;                       wp += (size_t)Bq * Tq * Nq * 2;  // 16.78 MB
    int4* aF = (int4*)wp;                                wp += 32 * 64 * 16;              // 32 KB
    int4* aB = (int4*)wp;                                wp += 32 * 64 * 16;              // 32 KB
    float* wsA  = (float*)wp;                            wp += (size_t)NFW * Bq * Nq * 4; // 4 MB
    float* wsB  = (float*)wp;                            wp += (size_t)NBW * Bq * Nq * 4; // 4 MB
    float* wsLa = (float*)wp;                            wp += NFW * Bq * 4;
    float* wsLb = (float*)wp;                            wp += NBW * Bq * 4;

    crf_prep_kernel<<<4096 + 16, 256, 0, stream>>>(
        emissions, transitions, token_sizes, eeh, aF, aB);
    crf_worker_kernel<<<Bq * WPC + Bq, 64, 0, stream>>>(
        emissions, eeh, aF, aB, token_sizes, targets, transitions, head, last,
        wsA, wsB, wsLa, wsLb, out);
    crf_combine_kernel<<<4 * Bq, 512, 0, stream>>>(wsA, wsB, wsLa, wsLb, out);
}

// Round 25
// 48.026 us; speedup vs baseline: 1.1037x; 1.1037x over previous
//
#include <hip/hip_runtime.h>
#include <math.h>

#define Bq 64
#define Tq 1024
#define Nq 128
#define SEG 129              // segments per chain (R22-proven)
#define NFW (SEG - 1)        // 128 forward workers: s = 1..128
#define NBW (SEG - 1)        // 128 backward workers: s = 2..129
#define WPC 16               // worker waves per chain (8 fwd + 8 bwd)
#define LN2 0.6931471805599453f

typedef __attribute__((ext_vector_type(8))) _Float16 half8;
typedef __attribute__((ext_vector_type(2))) _Float16 h2;
typedef __attribute__((ext_vector_type(4))) float f32x4;

union BU { int u[4]; int4 v; half8 h; };
union E8 { int2 v; h2 p[2]; };          // 4 f16
union E16 { int2 v2[2]; half8 h; };     // 8 f16 as two int2 loads

__device__ __forceinline__ int pk16(float a, float b) {
    auto p = __builtin_amdgcn_cvt_pkrtz(a, b);
    return *(int*)&p;
}

// Permuted m-slot map (R20-proven): k-slot (call q, lane-group g, word j) holds
//   m = 16*(2q + (j>>2)) + 4g + (j&3)  == D-slot (same lane, acc[2q+(j>>2)], reg j&3)
__device__ __forceinline__ int MMAP(int q, int g, int j) {
    return 16 * (2 * q + (j >> 2)) + 4 * g + (j & 3);
}

// ---------------------------------------------------------------------------
// Prep: blocks 0..4095   : eeh = (f16) exp(emissions), skipping rows >= tsz
//       blocks 4096..4111: pack exp(transitions) into PERMUTED fragment layout
//       blocks 4112..4175: gold-path score -> out[64+b]; zero out[b]
// Score rides free inside the memory-bound eeh pass (R22-proven placement).
// ---------------------------------------------------------------------------
__global__ __launch_bounds__(256)
void crf_prep_kernel(const float* __restrict__ em,
                     const float* __restrict__ trans,
                     const int* __restrict__ token_sizes,
                     const int* __restrict__ targets,
                     const float* __restrict__ head,
                     const float* __restrict__ last,
                     _Float16* __restrict__ eeh,
                     int4* __restrict__ aF, int4* __restrict__ aB,
                     float* __restrict__ out) {
    const int bid = blockIdx.x;
    const int tid = threadIdx.x;
    if (bid < 4096) {
        // each block covers 2048 contiguous elements = 16 rows of one chain
        const int b = bid >> 6;
        const int row0 = (bid & 63) * 16;
        if (row0 >= token_sizes[b]) return;   // rows never read by workers
        const size_t i = ((size_t)bid * 256 + tid) * 8;
        const float4* src = (const float4*)(em + i);
        float4 x0 = src[0], x1 = src[1];
        BU r;
        r.u[0] = pk16(__expf(x0.x), __expf(x0.y));
        r.u[1] = pk16(__expf(x0.z), __expf(x0.w));
        r.u[2] = pk16(__expf(x1.x), __expf(x1.y));
        r.u[3] = pk16(__expf(x1.z), __expf(x1.w));
        *(int4*)(eeh + i) = r.v;
        return;
    }
    if (bid < 4112) {
        const int fb = bid - 4096;            // 0..7 aF, 8..15 aB
        const bool fwd = (fb < 8);
        const int kf = (fb & 7) * 4 + (tid >> 6);   // fragment 0..31
        const int L = tid & 63;
        const int c = L & 15, g = L >> 4;
        const int r = kf >> 2, q = kf & 3;
        BU v;
        #pragma unroll
        for (int j = 0; j < 8; ++j) {
            const int m = MMAP(q, g, j);
            const int n = 16 * r + c;
            const float tv = fwd ? trans[m * Nq + n] : trans[n * Nq + m];
            v.h[j] = (_Float16)__expf(tv);
        }
        (fwd ? aF : aB)[kf * 64 + L] = v.v;
        return;
    }
    // ---------------- score path (one 256-thread block per chain) ----------
    {
        const int b = bid - 4112;
        const int tsz = token_sizes[b];
        const int* tg = targets + b * Tq;
        const float* emc = em + (size_t)b * Tq * Nq;
        float sc = 0.f;
        for (int t = tid; t < tsz; t += 256) {
            int cur = tg[t];
            sc += emc[(size_t)t * Nq + cur];
            if (t >= 1) sc += trans[tg[t - 1] * Nq + cur];
        }
        #pragma unroll
        for (int off = 32; off >= 1; off >>= 1)
            sc += __shfl_xor(sc, off, 64);
        __shared__ float wsum[4];
        if ((tid & 63) == 0) wsum[tid >> 6] = sc;
        __syncthreads();
        if (tid == 0) {
            float tot = (wsum[0] + wsum[1]) + (wsum[2] + wsum[3]);
            out[Bq + b] = tot + head[tg[0]] + last[tg[tsz - 1]];
            out[b] = 0.0f;                 // zero logZ slot for combine atomics
        }
    }
}

// ---------------------------------------------------------------------------
// FWD step — R20/R22-proven body (lane-local relayout, f16 ee from eeh).
// ---------------------------------------------------------------------------
__device__ __forceinline__ void fwd_step(
    int k, int lenc, int lo, int hi, int g,
    const _Float16* __restrict__ eeh_c,
    const half8 (&afrag)[32], BU (&bf)[4],
    E8 (&eeCur)[8], E8 (&eeNxt)[8], int& Ecum)
{
    f32x4 acc[8];
    #pragma unroll
    for (int r = 0; r < 8; ++r) {
        f32x4 z = {0.f, 0.f, 0.f, 0.f};
        z = __builtin_amdgcn_mfma_f32_16x16x32_f16(afrag[r*4+0], bf[0].h, z, 0, 0, 0);
        z = __builtin_amdgcn_mfma_f32_16x16x32_f16(afrag[r*4+1], bf[1].h, z, 0, 0, 0);
        z = __builtin_amdgcn_mfma_f32_16x16x32_f16(afrag[r*4+2], bf[2].h, z, 0, 0, 0);
        z = __builtin_amdgcn_mfma_f32_16x16x32_f16(afrag[r*4+3], bf[3].h, z, 0, 0, 0);
        acc[r] = z;
    }
    {   // prefetch next step's ee row (D layout: 8 x 8B per lane)
        const int tn = min(lo + k, hi);
        const _Float16* bp = eeh_c + (size_t)tn * Nq;
        #pragma unroll
        for (int r = 0; r < 8; ++r)
            eeNxt[r].v = *(const int2*)(bp + 16*r + 4*g);
    }
    float w[32];
    float mx = 0.f;
    #pragma unroll
    for (int r = 0; r < 8; ++r) {
        #pragma unroll
        for (int i = 0; i < 4; ++i) {
            const float ee = (float)eeCur[r].p[i >> 1][i & 1];
            const float wv = acc[r][i] * ee;
            w[r*4+i] = wv;
            mx = fmaxf(mx, wv);
        }
    }
    mx = fmaxf(mx, __shfl_xor(mx, 16, 64));
    mx = fmaxf(mx, __shfl_xor(mx, 32, 64));
    const int eb = (__float_as_int(mx) >> 23) & 255;
    const float sig = __int_as_float((253 - eb) << 23);
    const bool act = (k <= lenc);
    #pragma unroll
    for (int q = 0; q < 4; ++q) {   // D -> B: lane-local (permuted-E layout)
        const int n0 = pk16(w[8*q+0]*sig, w[8*q+1]*sig);
        const int n1 = pk16(w[8*q+2]*sig, w[8*q+3]*sig);
        const int n2 = pk16(w[8*q+4]*sig, w[8*q+5]*sig);
        const int n3 = pk16(w[8*q+6]*sig, w[8*q+7]*sig);
        bf[q].u[0] = act ? n0 : bf[q].u[0];
        bf[q].u[1] = act ? n1 : bf[q].u[1];
        bf[q].u[2] = act ? n2 : bf[q].u[2];
        bf[q].u[3] = act ? n3 : bf[q].u[3];
    }
    Ecum += act ? (eb - 126) : 0;
}

// ---------------------------------------------------------------------------
// BWD step — R20/R22-proven body (ee pk_mul on B operand; lane-local relayout).
// ---------------------------------------------------------------------------
__device__ __forceinline__ void bwd_step(
    int k, int lenc, int lo, int hi, int g,
    const _Float16* __restrict__ eeh_c,
    const half8 (&afrag)[32], BU (&bf)[4],
    E16 (&eeCur)[4], E16 (&eeNxt)[4], int& Ecum)
{
    BU beff[4];
    #pragma unroll
    for (int q = 0; q < 4; ++q) beff[q].h = bf[q].h * eeCur[q].h;  // v_pk_mul_f16
    f32x4 acc[8];
    #pragma unroll
    for (int r = 0; r < 8; ++r) {
        f32x4 z = {0.f, 0.f, 0.f, 0.f};
        z = __builtin_amdgcn_mfma_f32_16x16x32_f16(afrag[r*4+0], beff[0].h, z, 0, 0, 0);
        z = __builtin_amdgcn_mfma_f32_16x16x32_f16(afrag[r*4+1], beff[1].h, z, 0, 0, 0);
        z = __builtin_amdgcn_mfma_f32_16x16x32_f16(afrag[r*4+2], beff[2].h, z, 0, 0, 0);
        z = __builtin_amdgcn_mfma_f32_16x16x32_f16(afrag[r*4+3], beff[3].h, z, 0, 0, 0);
        acc[r] = z;
    }
    {   // prefetch next step's ee row (permuted B layout: 2 int2 per q)
        const int tn = max(hi - k, lo);
        const _Float16* bp = eeh_c + (size_t)tn * Nq;
        #pragma unroll
        for (int q = 0; q < 4; ++q) {
            eeNxt[q].v2[0] = *(const int2*)(bp + 32*q + 4*g);
            eeNxt[q].v2[1] = *(const int2*)(bp + 32*q + 16 + 4*g);
        }
    }
    float mx = 0.f;
    #pragma unroll
    for (int r = 0; r < 8; ++r) {
        #pragma unroll
        for (int i = 0; i < 4; ++i) mx = fmaxf(mx, acc[r][i]);
    }
    mx = fmaxf(mx, __shfl_xor(mx, 16, 64));
    mx = fmaxf(mx, __shfl_xor(mx, 32, 64));
    const int eb = (__float_as_int(mx) >> 23) & 255;
    const float sig = __int_as_float((253 - eb) << 23);
    const bool act = (k <= lenc);
    #pragma unroll
    for (int q = 0; q < 4; ++q) {
        const int n0 = pk16(acc[2*q][0]*sig,   acc[2*q][1]*sig);
        const int n1 = pk16(acc[2*q][2]*sig,   acc[2*q][3]*sig);
        const int n2 = pk16(acc[2*q+1][0]*sig, acc[2*q+1][1]*sig);
        const int n3 = pk16(acc[2*q+1][2]*sig, acc[2*q+1][3]*sig);
        bf[q].u[0] = act ? n0 : bf[q].u[0];
        bf[q].u[1] = act ? n1 : bf[q].u[1];
        bf[q].u[2] = act ? n2 : bf[q].u[2];
        bf[q].u[3] = act ? n3 : bf[q].u[3];
    }
    Ecum += act ? (eb - 126) : 0;
}

// ---------------------------------------------------------------------------
// Blocks 0..1023: worker waves only. bid: chain b=bid>>4, wv=bid&15.
// Worker vectors stored f32 in natural state order (R22-proven format).
// ---------------------------------------------------------------------------
__global__ __launch_bounds__(64, 1)
void crf_worker_kernel(const float* __restrict__ emissions,
                       const _Float16* __restrict__ eeh,
                       const int4* __restrict__ aF,
                       const int4* __restrict__ aB,
                       const int* __restrict__ token_sizes,
                       const float* __restrict__ head,
                       const float* __restrict__ last,
                       float* __restrict__ wsA, float* __restrict__ wsB,
                       float* __restrict__ wsLa, float* __restrict__ wsLb) {
    const int L = threadIdx.x;
    const int bid = blockIdx.x;

    const int b = bid >> 4;
    const int wv = bid & 15;
    const bool isFwd = (wv < 8);
    const int half_ = wv & 7;
    const int c = L & 15;
    const int g = L >> 4;
    const int s = (isFwd ? 1 : 2) + 16 * half_ + c;

    const float* em_c = emissions + (size_t)b * Tq * Nq;
    const _Float16* eeh_c = eeh + (size_t)b * Tq * Nq;
    const int tsz = token_sizes[b];
    const int nst = tsz - 1;
    const int base = nst / SEG;              // >= 3
    const int rem = nst % SEG;
    const int lo = 1 + (s - 1) * base + min(s - 1, rem);
    const int lenc = base + ((s <= rem) ? 1 : 0);
    const int hi = lo + lenc - 1;
    const int kmax = base + 1;

    // A fragments: 32 coalesced b128 loads (permuted layout from prep)
    half8 afrag[32];
    {
        const int4* asrc = isFwd ? aF : aB;
        #pragma unroll
        for (int kf = 0; kf < 32; ++kf) {
            BU t; t.v = asrc[kf * 64 + L];
            afrag[kf] = t.h;
        }
    }

    // init vector in PERMUTED B layout
    BU bf[4];
    float M0c;
    {
        float a0[32];
        float mx = -1e30f;
        #pragma unroll
        for (int q = 0; q < 4; ++q) {
            #pragma unroll
            for (int j2 = 0; j2 < 8; ++j2) {
                const int m = MMAP(q, g, j2);
                float v;
                if (isFwd) v = (s == 1)   ? (head[m] + em_c[m]) : 0.f;
                else       v = (s == SEG) ? last[m]             : 0.f;
                a0[q*8+j2] = v;
                mx = fmaxf(mx, v);
            }
        }
        mx = fmaxf(mx, __shfl_xor(mx, 16, 64));
        mx = fmaxf(mx, __shfl_xor(mx, 32, 64));
        M0c = mx;
        #pragma unroll
        for (int q = 0; q < 4; ++q) {
            #pragma unroll
            for (int p = 0; p < 4; ++p)
                bf[q].u[p] = pk16(__expf(a0[q*8+2*p]   - M0c),
                                  __expf(a0[q*8+2*p+1] - M0c));
        }
    }

    int Ecum = 0;
    int k = 1;
    if (isFwd) {
        E8 eeA[8], eeB8[8];
        const _Float16* bp = eeh_c + (size_t)lo * Nq;
        #pragma unroll
        for (int r = 0; r < 8; ++r) eeA[r].v = *(const int2*)(bp + 16*r + 4*g);
        for (; k + 1 <= kmax; k += 2) {
            fwd_step(k,   lenc, lo, hi, g, eeh_c, afrag, bf, eeA, eeB8, Ecum);
            fwd_step(k+1, lenc, lo, hi, g, eeh_c, afrag, bf, eeB8, eeA, Ecum);
        }
        if (k <= kmax)
            fwd_step(k, lenc, lo, hi, g, eeh_c, afrag, bf, eeA, eeB8, Ecum);
    } else {
        E16 eeA[4], eeB8[4];
        const _Float16* bp = eeh_c + (size_t)hi * Nq;
        #pragma unroll
        for (int q = 0; q < 4; ++q) {
            eeA[q].v2[0] = *(const int2*)(bp + 32*q + 4*g);
            eeA[q].v2[1] = *(const int2*)(bp + 32*q + 16 + 4*g);
        }
        for (; k + 1 <= kmax; k += 2) {
            bwd_step(k,   lenc, lo, hi, g, eeh_c, afrag, bf, eeA, eeB8, Ecum);
            bwd_step(k+1, lenc, lo, hi, g, eeh_c, afrag, bf, eeB8, eeA, Ecum);
        }
        if (k <= kmax)
            bwd_step(k, lenc, lo, hi, g, eeh_c, afrag, bf, eeA, eeB8, Ecum);
    }

    // store vector (two contiguous float4 per call, natural state order) + ledger
    {
        float* dst = isFwd ? (wsA + ((size_t)(s - 1) * Bq + b) * Nq)
                           : (wsB + ((size_t)(s - 2) * Bq + b) * Nq);
        #pragma unroll
        for (int q = 0; q < 4; ++q) {
            f32x4 v0, v1;
            #pragma unroll
            for (int t = 0; t < 4; ++t) { v0[t] = (float)bf[q].h[t]; v1[t] = (float)bf[q].h[4+t]; }
            *(f32x4*)(dst + 32*q + 4*g)      = v0;
            *(f32x4*)(dst + 32*q + 16 + 4*g) = v1;
        }
        if (g == 0) {
            const float led = M0c + (float)Ecum * LN2;
            if (isFwd) wsLa[(s - 1) * Bq + b] = led;
            else       wsLb[(s - 2) * Bq + b] = led;
        }
    }
}

// ---------------------------------------------------------------------------
// Combine (rank-1 telescope, R22-proven junction math): 256 blocks
// (4 per chain x 8 waves = 32 waves/chain), each wave handles 4 of the 128
// junctions; per-wave partials atomicAdd into out[chain] (zeroed in prep).
//   j in 0..126 (s=j+2): term = log(B[j].A[j]) + La[j] - log(sum B[j])
//   j == 127 (top)     : term = log(B[127].A[127]) + La[127] + Lb[127]
// ---------------------------------------------------------------------------
__global__ __launch_bounds__(512)
void crf_combine_kernel(const float* __restrict__ wsA,
                        const float* __restrict__ wsB,
                        const float* __restrict__ wsLa,
                        const float* __restrict__ wsLb,
                        float* __restrict__ out) {
    const int chain = blockIdx.x >> 2;
    const int sub = blockIdx.x & 3;
    const int wq = sub * 8 + (threadIdx.x >> 6);   // wave index 0..31
    const int l = threadIdx.x & 63;

    float tot = 0.f;
    #pragma unroll
    for (int rep = 0; rep < 4; ++rep) {            // j = wq + 32*rep, 128 total
        const int j = wq + 32 * rep;
        const float* bb = wsB + ((size_t)j * Bq + chain) * Nq;
        const float* aa = wsA + ((size_t)j * Bq + chain) * Nq;
        float z = bb[l] * aa[l] + bb[l + 64] * aa[l + 64];
        float cc = bb[l] + bb[l + 64];
        #pragma unroll
        for (int off = 32; off >= 1; off >>= 1) {
            z  += __shfl_xor(z, off, 64);
            cc += __shfl_xor(cc, off, 64);
        }
        float term = __logf(z) + wsLa[j * Bq + chain];
        term += (j == NFW - 1) ? wsLb[(NBW - 1) * Bq + chain] : -__logf(cc);
        tot += term;
    }
    if (l == 0) atomicAdd(&out[chain], tot);
}

extern "C" void kernel_launch(void* const* d_in, const int* in_sizes, int n_in,
                              void* d_out, int out_size, void* d_ws, size_t ws_size,
                              hipStream_t stream) {
    const float* emissions   = (const float*)d_in[0];
    const int*   token_sizes = (const int*)d_in[1];
    const int*   targets     = (const int*)d_in[2];
    const float* transitions = (const float*)d_in[3];  // (1,1,128,128)
    const float* head        = (const float*)d_in[4];  // (1,1,128)
    const float* last        = (const float*)d_in[5];  // (1,1,128)
    float* out = (float*)d_out;                        // (2,64,1) flat

    char* wp = (char*)d_ws;
    _Float16* eeh = (_Float16*)wp;                       wp += (size_t)Bq * Tq * Nq * 2;  // 16.78 MB
    int4* aF = (int4*)wp;                                wp += 32 * 64 * 16;              // 32 KB
    int4* aB = (int4*)wp;                                wp += 32 * 64 * 16;              // 32 KB
    float* wsA  = (float*)wp;                            wp += (size_t)NFW * Bq * Nq * 4; // 4 MB
    float* wsB  = (float*)wp;                            wp += (size_t)NBW * Bq * Nq * 4; // 4 MB
    float* wsLa = (float*)wp;                            wp += NFW * Bq * 4;
    float* wsLb = (float*)wp;                            wp += NBW * Bq * 4;

    crf_prep_kernel<<<4096 + 16 + Bq, 256, 0, stream>>>(
        emissions, transitions, token_sizes, targets, head, last,
        eeh, aF, aB, out);
    crf_worker_kernel<<<Bq * WPC, 64, 0, stream>>>(
        emissions, eeh, aF, aB, token_sizes, head, last,
        wsA, wsB, wsLa, wsLb);
    crf_combine_kernel<<<4 * Bq, 512, 0, stream>>>(wsA, wsB, wsLa, wsLb, out);
}

// Round 26
// 38.594 us; speedup vs baseline: 1.3734x; 1.2444x over previous
//
#include <hip/hip_runtime.h>
#include <math.h>

#define Bq 64
#define Tq 1024
#define Nq 128
#define SEG 129              // segments per chain (R22-proven)
#define NFW (SEG - 1)        // 128 forward workers: s = 1..128
#define NBW (SEG - 1)        // 128 backward workers: s = 2..129
#define WPC 16               // worker waves per chain (8 fwd + 8 bwd)
#define LN2 0.6931471805599453f

typedef __attribute__((ext_vector_type(8))) _Float16 half8;
typedef __attribute__((ext_vector_type(2))) _Float16 h2;
typedef __attribute__((ext_vector_type(4))) float f32x4;

union BU { int u[4]; int4 v; half8 h; };
union E8 { int2 v; h2 p[2]; };          // 4 f16
union E16 { int2 v2[2]; half8 h; };     // 8 f16 as two int2 loads

__device__ __forceinline__ int pk16(float a, float b) {
    auto p = __builtin_amdgcn_cvt_pkrtz(a, b);
    return *(int*)&p;
}

// Permuted m-slot map (R20-proven): k-slot (call q, lane-group g, word j) holds
//   m = 16*(2q + (j>>2)) + 4g + (j&3)  == D-slot (same lane, acc[2q+(j>>2)], reg j&3)
__device__ __forceinline__ int MMAP(int q, int g, int j) {
    return 16 * (2 * q + (j >> 2)) + 4 * g + (j & 3);
}

// ---------------------------------------------------------------------------
// Prep: blocks 0..4095   : eeh = (f16) exp(emissions), skipping rows >= tsz
//       blocks 4096..4111: pack exp(transitions) into PERMUTED fragment layout
//       blocks 4112..4175: gold-path score -> out[64+b]
// Score rides free inside the memory-bound eeh pass (R22-proven placement).
// ---------------------------------------------------------------------------
__global__ __launch_bounds__(256)
void crf_prep_kernel(const float* __restrict__ em,
                     const float* __restrict__ trans,
                     const int* __restrict__ token_sizes,
                     const int* __restrict__ targets,
                     const float* __restrict__ head,
                     const float* __restrict__ last,
                     _Float16* __restrict__ eeh,
                     int4* __restrict__ aF, int4* __restrict__ aB,
                     float* __restrict__ out) {
    const int bid = blockIdx.x;
    const int tid = threadIdx.x;
    if (bid < 4096) {
        // each block covers 2048 contiguous elements = 16 rows of one chain
        const int b = bid >> 6;
        const int row0 = (bid & 63) * 16;
        if (row0 >= token_sizes[b]) return;   // rows never read by workers
        const size_t i = ((size_t)bid * 256 + tid) * 8;
        const float4* src = (const float4*)(em + i);
        float4 x0 = src[0], x1 = src[1];
        BU r;
        r.u[0] = pk16(__expf(x0.x), __expf(x0.y));
        r.u[1] = pk16(__expf(x0.z), __expf(x0.w));
        r.u[2] = pk16(__expf(x1.x), __expf(x1.y));
        r.u[3] = pk16(__expf(x1.z), __expf(x1.w));
        *(int4*)(eeh + i) = r.v;
        return;
    }
    if (bid < 4112) {
        const int fb = bid - 4096;            // 0..7 aF, 8..15 aB
        const bool fwd = (fb < 8);
        const int kf = (fb & 7) * 4 + (tid >> 6);   // fragment 0..31
        const int L = tid & 63;
        const int c = L & 15, g = L >> 4;
        const int r = kf >> 2, q = kf & 3;
        BU v;
        #pragma unroll
        for (int j = 0; j < 8; ++j) {
            const int m = MMAP(q, g, j);
            const int n = 16 * r + c;
            const float tv = fwd ? trans[m * Nq + n] : trans[n * Nq + m];
            v.h[j] = (_Float16)__expf(tv);
        }
        (fwd ? aF : aB)[kf * 64 + L] = v.v;
        return;
    }
    // ---------------- score path (one 256-thread block per chain) ----------
    {
        const int b = bid - 4112;
        const int tsz = token_sizes[b];
        const int* tg = targets + b * Tq;
        const float* emc = em + (size_t)b * Tq * Nq;
        float sc = 0.f;
        for (int t = tid; t < tsz; t += 256) {
            int cur = tg[t];
            sc += emc[(size_t)t * Nq + cur];
            if (t >= 1) sc += trans[tg[t - 1] * Nq + cur];
        }
        #pragma unroll
        for (int off = 32; off >= 1; off >>= 1)
            sc += __shfl_xor(sc, off, 64);
        __shared__ float wsum[4];
        if ((tid & 63) == 0) wsum[tid >> 6] = sc;
        __syncthreads();
        if (tid == 0) {
            float tot = (wsum[0] + wsum[1]) + (wsum[2] + wsum[3]);
            out[Bq + b] = tot + head[tg[0]] + last[tg[tsz - 1]];
        }
    }
}

// ---------------------------------------------------------------------------
// FWD step — R20/R22-proven body (lane-local relayout, f16 ee from eeh).
// ---------------------------------------------------------------------------
__device__ __forceinline__ void fwd_step(
    int k, int lenc, int lo, int hi, int g,
    const _Float16* __restrict__ eeh_c,
    const half8 (&afrag)[32], BU (&bf)[4],
    E8 (&eeCur)[8], E8 (&eeNxt)[8], int& Ecum)
{
    f32x4 acc[8];
    #pragma unroll
    for (int r = 0; r < 8; ++r) {
        f32x4 z = {0.f, 0.f, 0.f, 0.f};
        z = __builtin_amdgcn_mfma_f32_16x16x32_f16(afrag[r*4+0], bf[0].h, z, 0, 0, 0);
        z = __builtin_amdgcn_mfma_f32_16x16x32_f16(afrag[r*4+1], bf[1].h, z, 0, 0, 0);
        z = __builtin_amdgcn_mfma_f32_16x16x32_f16(afrag[r*4+2], bf[2].h, z, 0, 0, 0);
        z = __builtin_amdgcn_mfma_f32_16x16x32_f16(afrag[r*4+3], bf[3].h, z, 0, 0, 0);
        acc[r] = z;
    }
    {   // prefetch next step's ee row (D layout: 8 x 8B per lane)
        const int tn = min(lo + k, hi);
        const _Float16* bp = eeh_c + (size_t)tn * Nq;
        #pragma unroll
        for (int r = 0; r < 8; ++r)
            eeNxt[r].v = *(const int2*)(bp + 16*r + 4*g);
    }
    float w[32];
    float mx = 0.f;
    #pragma unroll
    for (int r = 0; r < 8; ++r) {
        #pragma unroll
        for (int i = 0; i < 4; ++i) {
            const float ee = (float)eeCur[r].p[i >> 1][i & 1];
            const float wv = acc[r][i] * ee;
            w[r*4+i] = wv;
            mx = fmaxf(mx, wv);
        }
    }
    mx = fmaxf(mx, __shfl_xor(mx, 16, 64));
    mx = fmaxf(mx, __shfl_xor(mx, 32, 64));
    const int eb = (__float_as_int(mx) >> 23) & 255;
    const float sig = __int_as_float((253 - eb) << 23);
    const bool act = (k <= lenc);
    #pragma unroll
    for (int q = 0; q < 4; ++q) {   // D -> B: lane-local (permuted-E layout)
        const int n0 = pk16(w[8*q+0]*sig, w[8*q+1]*sig);
        const int n1 = pk16(w[8*q+2]*sig, w[8*q+3]*sig);
        const int n2 = pk16(w[8*q+4]*sig, w[8*q+5]*sig);
        const int n3 = pk16(w[8*q+6]*sig, w[8*q+7]*sig);
        bf[q].u[0] = act ? n0 : bf[q].u[0];
        bf[q].u[1] = act ? n1 : bf[q].u[1];
        bf[q].u[2] = act ? n2 : bf[q].u[2];
        bf[q].u[3] = act ? n3 : bf[q].u[3];
    }
    Ecum += act ? (eb - 126) : 0;
}

// ---------------------------------------------------------------------------
// BWD step — R20/R22-proven body (ee pk_mul on B operand; lane-local relayout).
// ---------------------------------------------------------------------------
__device__ __forceinline__ void bwd_step(
    int k, int lenc, int lo, int hi, int g,
    const _Float16* __restrict__ eeh_c,
    const half8 (&afrag)[32], BU (&bf)[4],
    E16 (&eeCur)[4], E16 (&eeNxt)[4], int& Ecum)
{
    BU beff[4];
    #pragma unroll
    for (int q = 0; q < 4; ++q) beff[q].h = bf[q].h * eeCur[q].h;  // v_pk_mul_f16
    f32x4 acc[8];
    #pragma unroll
    for (int r = 0; r < 8; ++r) {
        f32x4 z = {0.f, 0.f, 0.f, 0.f};
        z = __builtin_amdgcn_mfma_f32_16x16x32_f16(afrag[r*4+0], beff[0].h, z, 0, 0, 0);
        z = __builtin_amdgcn_mfma_f32_16x16x32_f16(afrag[r*4+1], beff[1].h, z, 0, 0, 0);
        z = __builtin_amdgcn_mfma_f32_16x16x32_f16(afrag[r*4+2], beff[2].h, z, 0, 0, 0);
        z = __builtin_amdgcn_mfma_f32_16x16x32_f16(afrag[r*4+3], beff[3].h, z, 0, 0, 0);
        acc[r] = z;
    }
    {   // prefetch next step's ee row (permuted B layout: 2 int2 per q)
        const int tn = max(hi - k, lo);
        const _Float16* bp = eeh_c + (size_t)tn * Nq;
        #pragma unroll
        for (int q = 0; q < 4; ++q) {
            eeNxt[q].v2[0] = *(const int2*)(bp + 32*q + 4*g);
            eeNxt[q].v2[1] = *(const int2*)(bp + 32*q + 16 + 4*g);
        }
    }
    float mx = 0.f;
    #pragma unroll
    for (int r = 0; r < 8; ++r) {
        #pragma unroll
        for (int i = 0; i < 4; ++i) mx = fmaxf(mx, acc[r][i]);
    }
    mx = fmaxf(mx, __shfl_xor(mx, 16, 64));
    mx = fmaxf(mx, __shfl_xor(mx, 32, 64));
    const int eb = (__float_as_int(mx) >> 23) & 255;
    const float sig = __int_as_float((253 - eb) << 23);
    const bool act = (k <= lenc);
    #pragma unroll
    for (int q = 0; q < 4; ++q) {
        const int n0 = pk16(acc[2*q][0]*sig,   acc[2*q][1]*sig);
        const int n1 = pk16(acc[2*q][2]*sig,   acc[2*q][3]*sig);
        const int n2 = pk16(acc[2*q+1][0]*sig, acc[2*q+1][1]*sig);
        const int n3 = pk16(acc[2*q+1][2]*sig, acc[2*q+1][3]*sig);
        bf[q].u[0] = act ? n0 : bf[q].u[0];
        bf[q].u[1] = act ? n1 : bf[q].u[1];
        bf[q].u[2] = act ? n2 : bf[q].u[2];
        bf[q].u[3] = act ? n3 : bf[q].u[3];
    }
    Ecum += act ? (eb - 126) : 0;
}

// ---------------------------------------------------------------------------
// Blocks 0..1023: worker waves only. bid: chain b=bid>>4, wv=bid&15.
// Worker vectors stored f32 in natural state order (R22-proven format).
// ---------------------------------------------------------------------------
__global__ __launch_bounds__(64, 1)
void crf_worker_kernel(const float* __restrict__ emissions,
                       const _Float16* __restrict__ eeh,
                       const int4* __restrict__ aF,
                       const int4* __restrict__ aB,
                       const int* __restrict__ token_sizes,
                       const float* __restrict__ head,
                       const float* __restrict__ last,
                       float* __restrict__ wsA, float* __restrict__ wsB,
                       float* __restrict__ wsLa, float* __restrict__ wsLb) {
    const int L = threadIdx.x;
    const int bid = blockIdx.x;

    const int b = bid >> 4;
    const int wv = bid & 15;
    const bool isFwd = (wv < 8);
    const int half_ = wv & 7;
    const int c = L & 15;
    const int g = L >> 4;
    const int s = (isFwd ? 1 : 2) + 16 * half_ + c;

    const float* em_c = emissions + (size_t)b * Tq * Nq;
    const _Float16* eeh_c = eeh + (size_t)b * Tq * Nq;
    const int tsz = token_sizes[b];
    const int nst = tsz - 1;
    const int base = nst / SEG;              // >= 3
    const int rem = nst % SEG;
    const int lo = 1 + (s - 1) * base + min(s - 1, rem);
    const int lenc = base + ((s <= rem) ? 1 : 0);
    const int hi = lo + lenc - 1;
    const int kmax = base + 1;

    // A fragments: 32 coalesced b128 loads (permuted layout from prep)
    half8 afrag[32];
    {
        const int4* asrc = isFwd ? aF : aB;
        #pragma unroll
        for (int kf = 0; kf < 32; ++kf) {
            BU t; t.v = asrc[kf * 64 + L];
            afrag[kf] = t.h;
        }
    }

    // init vector in PERMUTED B layout
    BU bf[4];
    float M0c;
    {
        float a0[32];
        float mx = -1e30f;
        #pragma unroll
        for (int q = 0; q < 4; ++q) {
            #pragma unroll
            for (int j2 = 0; j2 < 8; ++j2) {
                const int m = MMAP(q, g, j2);
                float v;
                if (isFwd) v = (s == 1)   ? (head[m] + em_c[m]) : 0.f;
                else       v = (s == SEG) ? last[m]             : 0.f;
                a0[q*8+j2] = v;
                mx = fmaxf(mx, v);
            }
        }
        mx = fmaxf(mx, __shfl_xor(mx, 16, 64));
        mx = fmaxf(mx, __shfl_xor(mx, 32, 64));
        M0c = mx;
        #pragma unroll
        for (int q = 0; q < 4; ++q) {
            #pragma unroll
            for (int p = 0; p < 4; ++p)
                bf[q].u[p] = pk16(__expf(a0[q*8+2*p]   - M0c),
                                  __expf(a0[q*8+2*p+1] - M0c));
        }
    }

    int Ecum = 0;
    int k = 1;
    if (isFwd) {
        E8 eeA[8], eeB8[8];
        const _Float16* bp = eeh_c + (size_t)lo * Nq;
        #pragma unroll
        for (int r = 0; r < 8; ++r) eeA[r].v = *(const int2*)(bp + 16*r + 4*g);
        for (; k + 1 <= kmax; k += 2) {
            fwd_step(k,   lenc, lo, hi, g, eeh_c, afrag, bf, eeA, eeB8, Ecum);
            fwd_step(k+1, lenc, lo, hi, g, eeh_c, afrag, bf, eeB8, eeA, Ecum);
        }
        if (k <= kmax)
            fwd_step(k, lenc, lo, hi, g, eeh_c, afrag, bf, eeA, eeB8, Ecum);
    } else {
        E16 eeA[4], eeB8[4];
        const _Float16* bp = eeh_c + (size_t)hi * Nq;
        #pragma unroll
        for (int q = 0; q < 4; ++q) {
            eeA[q].v2[0] = *(const int2*)(bp + 32*q + 4*g);
            eeA[q].v2[1] = *(const int2*)(bp + 32*q + 16 + 4*g);
        }
        for (; k + 1 <= kmax; k += 2) {
            bwd_step(k,   lenc, lo, hi, g, eeh_c, afrag, bf, eeA, eeB8, Ecum);
            bwd_step(k+1, lenc, lo, hi, g, eeh_c, afrag, bf, eeB8, eeA, Ecum);
        }
        if (k <= kmax)
            bwd_step(k, lenc, lo, hi, g, eeh_c, afrag, bf, eeA, eeB8, Ecum);
    }

    // store vector (two contiguous float4 per call, natural state order) + ledger
    {
        float* dst = isFwd ? (wsA + ((size_t)(s - 1) * Bq + b) * Nq)
                           : (wsB + ((size_t)(s - 2) * Bq + b) * Nq);
        #pragma unroll
        for (int q = 0; q < 4; ++q) {
            f32x4 v0, v1;
            #pragma unroll
            for (int t = 0; t < 4; ++t) { v0[t] = (float)bf[q].h[t]; v1[t] = (float)bf[q].h[4+t]; }
            *(f32x4*)(dst + 32*q + 4*g)      = v0;
            *(f32x4*)(dst + 32*q + 16 + 4*g) = v1;
        }
        if (g == 0) {
            const float led = M0c + (float)Ecum * LN2;
            if (isFwd) wsLa[(s - 1) * Bq + b] = led;
            else       wsLb[(s - 2) * Bq + b] = led;
        }
    }
}

// ---------------------------------------------------------------------------
// Combine (rank-1 telescope, R22/R24-proven junction math): one block per
// chain, 1024 threads = 16 waves; wave wq handles junctions j = wq + 16*rep
// (8 each); 16 partials through LDS; single write to out[chain]. No atomics.
//   j in 0..126 (s=j+2): term = log(B[j].A[j]) + La[j] - log(sum B[j])
//   j == 127 (top)     : term = log(B[127].A[127]) + La[127] + Lb[127]
// ---------------------------------------------------------------------------
__global__ __launch_bounds__(1024)
void crf_combine_kernel(const float* __restrict__ wsA,
                        const float* __restrict__ wsB,
                        const float* __restrict__ wsLa,
                        const float* __restrict__ wsLb,
                        float* __restrict__ out) {
    const int chain = blockIdx.x;
    const int wq = threadIdx.x >> 6;               // wave 0..15
    const int l = threadIdx.x & 63;
    __shared__ float part[16];

    float tot = 0.f;
    #pragma unroll
    for (int rep = 0; rep < 8; ++rep) {            // j = wq + 16*rep, 128 total
        const int j = wq + 16 * rep;
        const float* bb = wsB + ((size_t)j * Bq + chain) * Nq;
        const float* aa = wsA + ((size_t)j * Bq + chain) * Nq;
        float z = bb[l] * aa[l] + bb[l + 64] * aa[l + 64];
        float cc = bb[l] + bb[l + 64];
        #pragma unroll
        for (int off = 32; off >= 1; off >>= 1) {
            z  += __shfl_xor(z, off, 64);
            cc += __shfl_xor(cc, off, 64);
        }
        float term = __logf(z) + wsLa[j * Bq + chain];
        term += (j == NFW - 1) ? wsLb[(NBW - 1) * Bq + chain] : -__logf(cc);
        tot += term;
    }
    if (l == 0) part[wq] = tot;
    __syncthreads();
    if (threadIdx.x == 0) {
        float tz = 0.f;
        #pragma unroll
        for (int i = 0; i < 16; ++i) tz += part[i];
        out[chain] = tz;
    }
}

extern "C" void kernel_launch(void* const* d_in, const int* in_sizes, int n_in,
                              void* d_out, int out_size, void* d_ws, size_t ws_size,
                              hipStream_t stream) {
    const float* emissions   = (const float*)d_in[0];
    const int*   token_sizes = (const int*)d_in[1];
    const int*   targets     = (const int*)d_in[2];
    const float* transitions = (const float*)d_in[3];  // (1,1,128,128)
    const float* head        = (const float*)d_in[4];  // (1,1,128)
    const float* last        = (const float*)d_in[5];  // (1,1,128)
    float* out = (float*)d_out;                        // (2,64,1) flat

    char* wp = (char*)d_ws;
    _Float16* eeh = (_Float16*)wp;                       wp += (size_t)Bq * Tq * Nq * 2;  // 16.78 MB
    int4* aF = (int4*)wp;                                wp += 32 * 64 * 16;              // 32 KB
    int4* aB = (int4*)wp;                                wp += 32 * 64 * 16;              // 32 KB
    float* wsA  = (float*)wp;                            wp += (size_t)NFW * Bq * Nq * 4; // 4 MB
    float* wsB  = (float*)wp;                            wp += (size_t)NBW * Bq * Nq * 4; // 4 MB
    float* wsLa = (float*)wp;                            wp += NFW * Bq * 4;
    float* wsLb = (float*)wp;                            wp += NBW * Bq * 4;

    crf_prep_kernel<<<4096 + 16 + Bq, 256, 0, stream>>>(
        emissions, transitions, token_sizes, targets, head, last,
        eeh, aF, aB, out);
    crf_worker_kernel<<<Bq * WPC, 64, 0, stream>>>(
        emissions, eeh, aF, aB, token_sizes, head, last,
        wsA, wsB, wsLa, wsLb);
    crf_combine_kernel<<<Bq, 1024, 0, stream>>>(wsA, wsB, wsLa, wsLb, out);
}

// Round 27
// 36.916 us; speedup vs baseline: 1.4358x; 1.0455x over previous
//
#include <hip/hip_runtime.h>
#include <math.h>

#define Bq 64
#define Tq 1024
#define Nq 128
#define SEG 129              // segments per chain (R22/R26-proven)
#define NFW (SEG - 1)        // 128 forward workers: s = 1..128
#define NBW (SEG - 1)        // 128 backward workers: s = 2..129
#define WPC 16               // worker waves per chain (8 fwd + 8 bwd)
#define LN2 0.6931471805599453f

typedef __attribute__((ext_vector_type(8))) _Float16 half8;
typedef __attribute__((ext_vector_type(2))) _Float16 h2;
typedef __attribute__((ext_vector_type(4))) float f32x4;

union BU { int u[4]; int4 v; half8 h; };

__device__ __forceinline__ int pk16(float a, float b) {
    auto p = __builtin_amdgcn_cvt_pkrtz(a, b);
    return *(int*)&p;
}

// Permuted m-slot map (R20-proven): k-slot (call q, lane-group g, word j) holds
//   m = 16*(2q + (j>>2)) + 4g + (j&3)  == D-slot (same lane, acc[2q+(j>>2)], reg j&3)
__device__ __forceinline__ int MMAP(int q, int g, int j) {
    return 16 * (2 * q + (j >> 2)) + 4 * g + (j & 3);
}

// pack one emission row's B-layout slice for lane (g): positions 32q+4g+0..3
// and 32q+16+4g+0..3 -> int4 of 8 f16 = exp(row vals)
__device__ __forceinline__ int4 packRowQ(const float* __restrict__ bp, int q, int g) {
    const float4 x = *(const float4*)(bp + 32*q + 4*g);
    const float4 y = *(const float4*)(bp + 32*q + 16 + 4*g);
    return make_int4(pk16(__expf(x.x), __expf(x.y)),
                     pk16(__expf(x.z), __expf(x.w)),
                     pk16(__expf(y.x), __expf(y.y)),
                     pk16(__expf(y.z), __expf(y.w)));
}

// ---------------------------------------------------------------------------
// Prep: 16 blocks — pack exp(transitions) into PERMUTED fragment layout.
// ---------------------------------------------------------------------------
__global__ __launch_bounds__(256)
void crf_prep_kernel(const float* __restrict__ trans,
                     int4* __restrict__ aF, int4* __restrict__ aB) {
    const int fb = blockIdx.x;            // 0..7 aF, 8..15 aB
    const bool fwd = (fb < 8);
    const int kf = (fb & 7) * 4 + (threadIdx.x >> 6);   // fragment 0..31
    const int L = threadIdx.x & 63;
    const int c = L & 15, g = L >> 4;
    const int r = kf >> 2, q = kf & 3;
    BU v;
    #pragma unroll
    for (int j = 0; j < 8; ++j) {
        const int m = MMAP(q, g, j);
        const int n = 16 * r + c;
        const float tv = fwd ? trans[m * Nq + n] : trans[n * Nq + m];
        v.h[j] = (_Float16)__expf(tv);
    }
    (fwd ? aF : aB)[kf * 64 + L] = v.v;
}

// ---------------------------------------------------------------------------
// Unified step (R26 bwd_step body; ee from LDS stage). k is a call-site
// literal so eeL indexing is compile-time (rule #20).
//   beff = bf (x) ee ; acc = A beff (16 MFMA); normalize acc by per-column
//   power-of-2; predicated pack back into bf; exact integer ledger.
// ---------------------------------------------------------------------------
__device__ __forceinline__ void ustep(
    int k, int lenc, int L,
    const int4 (&eeL)[8][4][64],
    const half8 (&afrag)[32], BU (&bf)[4], int& Ecum)
{
    BU ee[4], beff[4];
    #pragma unroll
    for (int q = 0; q < 4; ++q) ee[q].v = eeL[k - 1][q][L];
    #pragma unroll
    for (int q = 0; q < 4; ++q) beff[q].h = bf[q].h * ee[q].h;  // v_pk_mul_f16
    f32x4 acc[8];
    #pragma unroll
    for (int r = 0; r < 8; ++r) {
        f32x4 z = {0.f, 0.f, 0.f, 0.f};
        z = __builtin_amdgcn_mfma_f32_16x16x32_f16(afrag[r*4+0], beff[0].h, z, 0, 0, 0);
        z = __builtin_amdgcn_mfma_f32_16x16x32_f16(afrag[r*4+1], beff[1].h, z, 0, 0, 0);
        z = __builtin_amdgcn_mfma_f32_16x16x32_f16(afrag[r*4+2], beff[2].h, z, 0, 0, 0);
        z = __builtin_amdgcn_mfma_f32_16x16x32_f16(afrag[r*4+3], beff[3].h, z, 0, 0, 0);
        acc[r] = z;
    }
    float mx = 0.f;
    #pragma unroll
    for (int r = 0; r < 8; ++r) {
        #pragma unroll
        for (int i = 0; i < 4; ++i) mx = fmaxf(mx, acc[r][i]);
    }
    mx = fmaxf(mx, __shfl_xor(mx, 16, 64));
    mx = fmaxf(mx, __shfl_xor(mx, 32, 64));
    const int eb = (__float_as_int(mx) >> 23) & 255;
    const float sig = __int_as_float((253 - eb) << 23);
    const bool act = (k <= lenc);
    #pragma unroll
    for (int q = 0; q < 4; ++q) {
        const int n0 = pk16(acc[2*q][0]*sig,   acc[2*q][1]*sig);
        const int n1 = pk16(acc[2*q][2]*sig,   acc[2*q][3]*sig);
        const int n2 = pk16(acc[2*q+1][0]*sig, acc[2*q+1][1]*sig);
        const int n3 = pk16(acc[2*q+1][2]*sig, acc[2*q+1][3]*sig);
        bf[q].u[0] = act ? n0 : bf[q].u[0];
        bf[q].u[1] = act ? n1 : bf[q].u[1];
        bf[q].u[2] = act ? n2 : bf[q].u[2];
        bf[q].u[3] = act ? n3 : bf[q].u[3];
    }
    Ecum += act ? (eb - 126) : 0;
}

// ---------------------------------------------------------------------------
// Worker: 1024 blocks (1 wave). bid: chain b=bid>>4, wv=bid&15 (0..7 fwd).
// FWD u-recursion: u_{k+1} = E^T(ee_k (x) u_k); eeL[0]=ones, eeL[i>=1]=row
// lo+i-1 (clamped to hi-1); final store v = u (x) ee_hi.  Consumes rows
// lo..hi exactly once == R26 FWD semantics.
// BWD unchanged semantics: eeL[i] = row max(hi-i, lo); steps consume hi..lo.
// Zero global memory in the step loop; ee staged in 32 KB LDS.
// ---------------------------------------------------------------------------
__global__ __launch_bounds__(64, 1)
void crf_worker_kernel(const float* __restrict__ emissions,
                       const int4* __restrict__ aF,
                       const int4* __restrict__ aB,
                       const int* __restrict__ token_sizes,
                       const float* __restrict__ head,
                       const float* __restrict__ last,
                       float* __restrict__ wsA, float* __restrict__ wsB,
                       float* __restrict__ wsLa, float* __restrict__ wsLb) {
    const int L = threadIdx.x;
    const int bid = blockIdx.x;

    __shared__ __align__(16) int4 eeL[8][4][64];   // [step][q][lane], 32 KB

    const int b = bid >> 4;
    const int wv = bid & 15;
    const bool isFwd = (wv < 8);
    const int half_ = wv & 7;
    const int c = L & 15;
    const int g = L >> 4;
    const int s = (isFwd ? 1 : 2) + 16 * half_ + c;

    const float* em_c = emissions + (size_t)b * Tq * Nq;
    const int tsz = token_sizes[b];
    const int nst = tsz - 1;
    const int base = nst / SEG;              // 3..7
    const int rem = nst % SEG;
    const int lo = 1 + (s - 1) * base + min(s - 1, rem);
    const int lenc = base + ((s <= rem) ? 1 : 0);   // 3..8, <= kmax
    const int hi = lo + lenc - 1;
    const int kmax = base + 1;               // 4..8, wave-uniform

    // A fragments: 32 coalesced b128 loads (permuted layout from prep)
    half8 afrag[32];
    {
        const int4* asrc = isFwd ? aF : aB;
        #pragma unroll
        for (int kf = 0; kf < 32; ++kf) {
            BU t; t.v = asrc[kf * 64 + L];
            afrag[kf] = t.h;
        }
    }

    // init vector in PERMUTED B layout (R26-proven)
    BU bf[4];
    float M0c;
    {
        float a0[32];
        float mx = -1e30f;
        #pragma unroll
        for (int q = 0; q < 4; ++q) {
            #pragma unroll
            for (int j2 = 0; j2 < 8; ++j2) {
                const int m = MMAP(q, g, j2);
                float v;
                if (isFwd) v = (s == 1)   ? (head[m] + em_c[m]) : 0.f;
                else       v = (s == SEG) ? last[m]             : 0.f;
                a0[q*8+j2] = v;
                mx = fmaxf(mx, v);
            }
        }
        mx = fmaxf(mx, __shfl_xor(mx, 16, 64));
        mx = fmaxf(mx, __shfl_xor(mx, 32, 64));
        M0c = mx;
        #pragma unroll
        for (int q = 0; q < 4; ++q) {
            #pragma unroll
            for (int p = 0; p < 4; ++p)
                bf[q].u[p] = pk16(__expf(a0[q*8+2*p]   - M0c),
                                  __expf(a0[q*8+2*p+1] - M0c));
        }
    }

    // ---- stage ee rows into LDS; FWD also keeps ee_hi in registers ----
    BU eeHi[4];
    if (isFwd) {
        const int one2 = pk16(1.0f, 1.0f);
        const int4 ones = make_int4(one2, one2, one2, one2);
        #pragma unroll
        for (int q = 0; q < 4; ++q) eeL[0][q][L] = ones;
        #pragma unroll
        for (int i = 1; i < 8; ++i) {
            const int row = min(lo + i - 1, hi - 1);
            const float* bp = em_c + (size_t)row * Nq;
            #pragma unroll
            for (int q = 0; q < 4; ++q) eeL[i][q][L] = packRowQ(bp, q, g);
        }
        const float* bp = em_c + (size_t)hi * Nq;
        #pragma unroll
        for (int q = 0; q < 4; ++q) eeHi[q].v = packRowQ(bp, q, g);
    } else {
        #pragma unroll
        for (int i = 0; i < 8; ++i) {
            const int row = max(hi - i, lo);
            const float* bp = em_c + (size_t)row * Nq;
            #pragma unroll
            for (int q = 0; q < 4; ++q) eeL[i][q][L] = packRowQ(bp, q, g);
        }
    }
    __syncthreads();   // single-wave block: cheap LDS write->read fence

    int Ecum = 0;
    ustep(1, lenc, L, eeL, afrag, bf, Ecum);
    ustep(2, lenc, L, eeL, afrag, bf, Ecum);
    ustep(3, lenc, L, eeL, afrag, bf, Ecum);
    ustep(4, lenc, L, eeL, afrag, bf, Ecum);
    if (kmax >= 5) ustep(5, lenc, L, eeL, afrag, bf, Ecum);
    if (kmax >= 6) ustep(6, lenc, L, eeL, afrag, bf, Ecum);
    if (kmax >= 7) ustep(7, lenc, L, eeL, afrag, bf, Ecum);
    if (kmax >= 8) ustep(8, lenc, L, eeL, afrag, bf, Ecum);

    // store vector (natural state order, f32) + ledger.
    // FWD: v = u (x) ee_hi applied here (completes the u-recursion).
    {
        float* dst = isFwd ? (wsA + ((size_t)(s - 1) * Bq + b) * Nq)
                           : (wsB + ((size_t)(s - 2) * Bq + b) * Nq);
        #pragma unroll
        for (int q = 0; q < 4; ++q) {
            f32x4 v0, v1;
            #pragma unroll
            for (int t = 0; t < 4; ++t) {
                float m0 = isFwd ? (float)eeHi[q].h[t]     : 1.0f;
                float m1 = isFwd ? (float)eeHi[q].h[4 + t] : 1.0f;
                v0[t] = (float)bf[q].h[t]     * m0;
                v1[t] = (float)bf[q].h[4 + t] * m1;
            }
            *(f32x4*)(dst + 32*q + 4*g)      = v0;
            *(f32x4*)(dst + 32*q + 16 + 4*g) = v1;
        }
        if (g == 0) {
            const float led = M0c + (float)Ecum * LN2;
            if (isFwd) wsLa[(s - 1) * Bq + b] = led;
            else       wsLb[(s - 2) * Bq + b] = led;
        }
    }
}

// ---------------------------------------------------------------------------
// Combine + score. Blocks 0..63: rank-1 telescope (R26-proven, 16 waves,
// LDS partials, no atomics). Blocks 64..127: gold-path score, 1024 threads
// -> one gather per thread.
// ---------------------------------------------------------------------------
__global__ __launch_bounds__(1024)
void crf_combine_kernel(const float* __restrict__ wsA,
                        const float* __restrict__ wsB,
                        const float* __restrict__ wsLa,
                        const float* __restrict__ wsLb,
                        const float* __restrict__ emissions,
                        const int* __restrict__ token_sizes,
                        const int* __restrict__ targets,
                        const float* __restrict__ transitions,
                        const float* __restrict__ head,
                        const float* __restrict__ last,
                        float* __restrict__ out) {
    const int bid = blockIdx.x;
    const int tid = threadIdx.x;
    __shared__ float part[16];

    if (bid < Bq) {
        const int chain = bid;
        const int wq = tid >> 6;                   // wave 0..15
        const int l = tid & 63;
        float tot = 0.f;
        #pragma unroll
        for (int rep = 0; rep < 8; ++rep) {        // j = wq + 16*rep, 128 total
            const int j = wq + 16 * rep;
            const float* bb = wsB + ((size_t)j * Bq + chain) * Nq;
            const float* aa = wsA + ((size_t)j * Bq + chain) * Nq;
            float z = bb[l] * aa[l] + bb[l + 64] * aa[l + 64];
            float cc = bb[l] + bb[l + 64];
            #pragma unroll
            for (int off = 32; off >= 1; off >>= 1) {
                z  += __shfl_xor(z, off, 64);
                cc += __shfl_xor(cc, off, 64);
            }
            float term = __logf(z) + wsLa[j * Bq + chain];
            term += (j == NFW - 1) ? wsLb[(NBW - 1) * Bq + chain] : -__logf(cc);
            tot += term;
        }
        if (l == 0) part[wq] = tot;
        __syncthreads();
        if (tid == 0) {
            float tz = 0.f;
            #pragma unroll
            for (int i = 0; i < 16; ++i) tz += part[i];
            out[chain] = tz;
        }
        return;
    }
    // ---------------- score path ----------------
    {
        const int b = bid - Bq;
        const int tsz = token_sizes[b];
        const int* tg = targets + b * Tq;
        const float* emc = emissions + (size_t)b * Tq * Nq;
        float sc = 0.f;
        if (tid < tsz) {
            const int cur = tg[tid];
            sc = emc[(size_t)tid * Nq + cur];
            if (tid >= 1) sc += transitions[tg[tid - 1] * Nq + cur];
        }
        #pragma unroll
        for (int off = 32; off >= 1; off >>= 1)
            sc += __shfl_xor(sc, off, 64);
        if ((tid & 63) == 0) part[tid >> 6] = sc;
        __syncthreads();
        if (tid == 0) {
            float tot = 0.f;
            #pragma unroll
            for (int i = 0; i < 16; ++i) tot += part[i];
            out[Bq + b] = tot + head[tg[0]] + last[tg[tsz - 1]];
        }
    }
}

extern "C" void kernel_launch(void* const* d_in, const int* in_sizes, int n_in,
                              void* d_out, int out_size, void* d_ws, size_t ws_size,
                              hipStream_t stream) {
    const float* emissions   = (const float*)d_in[0];
    const int*   token_sizes = (const int*)d_in[1];
    const int*   targets     = (const int*)d_in[2];
    const float* transitions = (const float*)d_in[3];  // (1,1,128,128)
    const float* head        = (const float*)d_in[4];  // (1,1,128)
    const float* last        = (const float*)d_in[5];  // (1,1,128)
    float* out = (float*)d_out;                        // (2,64,1) flat

    char* wp = (char*)d_ws;
    int4* aF = (int4*)wp;                                wp += 32 * 64 * 16;              // 32 KB
    int4* aB = (int4*)wp;                                wp += 32 * 64 * 16;              // 32 KB
    float* wsA  = (float*)wp;                            wp += (size_t)NFW * Bq * Nq * 4; // 4 MB
    float* wsB  = (float*)wp;                            wp += (size_t)NBW * Bq * Nq * 4; // 4 MB
    float* wsLa = (float*)wp;                            wp += NFW * Bq * 4;
    float* wsLb = (float*)wp;                            wp += NBW * Bq * 4;

    crf_prep_kernel<<<16, 256, 0, stream>>>(transitions, aF, aB);
    crf_worker_kernel<<<Bq * WPC, 64, 0, stream>>>(
        emissions, aF, aB, token_sizes, head, last,
        wsA, wsB, wsLa, wsLb);
    crf_combine_kernel<<<2 * Bq, 1024, 0, stream>>>(
        wsA, wsB, wsLa, wsLb,
        emissions, token_sizes, targets, transitions, head, last, out);
}

// Round 28
// 36.494 us; speedup vs baseline: 1.4524x; 1.0116x over previous
//
#include <hip/hip_runtime.h>
#include <math.h>

#define Bq 64
#define Tq 1024
#define Nq 128
#define SEG 129              // segments per chain (R22/R26/R27-proven)
#define NFW (SEG - 1)        // 128 forward results: s = 1..128
#define NBW (SEG - 1)        // 128 backward results: s = 2..129
#define BPC 9                // paired 2-wave blocks per chain (144 slots >= 129)
#define LN2 0.6931471805599453f

typedef __attribute__((ext_vector_type(8))) _Float16 half8;
typedef __attribute__((ext_vector_type(2))) _Float16 h2;
typedef __attribute__((ext_vector_type(4))) float f32x4;

union BU { int u[4]; int4 v; half8 h; };

__device__ __forceinline__ int pk16(float a, float b) {
    auto p = __builtin_amdgcn_cvt_pkrtz(a, b);
    return *(int*)&p;
}

// Permuted m-slot map (R20-proven): k-slot (call q, lane-group g, word j) holds
//   m = 16*(2q + (j>>2)) + 4g + (j&3)  == D-slot (same lane, acc[2q+(j>>2)], reg j&3)
__device__ __forceinline__ int MMAP(int q, int g, int j) {
    return 16 * (2 * q + (j >> 2)) + 4 * g + (j & 3);
}

// pack one emission row's B-layout slice for lane-group g: positions
// 32q+4g+0..3 and 32q+16+4g+0..3 -> int4 of 8 f16 = exp(row vals)
__device__ __forceinline__ int4 packRowQ(const float* __restrict__ bp, int q, int g) {
    const float4 x = *(const float4*)(bp + 32*q + 4*g);
    const float4 y = *(const float4*)(bp + 32*q + 16 + 4*g);
    return make_int4(pk16(__expf(x.x), __expf(x.y)),
                     pk16(__expf(x.z), __expf(x.w)),
                     pk16(__expf(y.x), __expf(y.y)),
                     pk16(__expf(y.z), __expf(y.w)));
}

// ---------------------------------------------------------------------------
// Prep: 16 blocks — pack exp(transitions) into PERMUTED fragment layout.
// ---------------------------------------------------------------------------
__global__ __launch_bounds__(256)
void crf_prep_kernel(const float* __restrict__ trans,
                     int4* __restrict__ aF, int4* __restrict__ aB) {
    const int fb = blockIdx.x;            // 0..7 aF, 8..15 aB
    const bool fwd = (fb < 8);
    const int kf = (fb & 7) * 4 + (threadIdx.x >> 6);   // fragment 0..31
    const int L = threadIdx.x & 63;
    const int c = L & 15, g = L >> 4;
    const int r = kf >> 2, q = kf & 3;
    BU v;
    #pragma unroll
    for (int j = 0; j < 8; ++j) {
        const int m = MMAP(q, g, j);
        const int n = 16 * r + c;
        const float tv = fwd ? trans[m * Nq + n] : trans[n * Nq + m];
        v.h[j] = (_Float16)__expf(tv);
    }
    (fwd ? aF : aB)[kf * 64 + L] = v.v;
}

// ---------------------------------------------------------------------------
// One step (R27 ustep body). useEE=false skips the ee multiply (fwd step 1).
// eeIdx may be runtime (LDS dynamic addressing).
// ---------------------------------------------------------------------------
__device__ __forceinline__ void pstep(
    int k, int lenc, int eeIdx, bool useEE, int L,
    const int4 (&eeL)[8][4][64],
    const half8 (&afrag)[32], BU (&bf)[4], int& Ecum)
{
    BU beff[4];
    if (useEE) {
        #pragma unroll
        for (int q = 0; q < 4; ++q) {
            BU e; e.v = eeL[eeIdx][q][L];
            beff[q].h = bf[q].h * e.h;        // v_pk_mul_f16
        }
    } else {
        #pragma unroll
        for (int q = 0; q < 4; ++q) beff[q] = bf[q];
    }
    f32x4 acc[8];
    #pragma unroll
    for (int r = 0; r < 8; ++r) {
        f32x4 z = {0.f, 0.f, 0.f, 0.f};
        z = __builtin_amdgcn_mfma_f32_16x16x32_f16(afrag[r*4+0], beff[0].h, z, 0, 0, 0);
        z = __builtin_amdgcn_mfma_f32_16x16x32_f16(afrag[r*4+1], beff[1].h, z, 0, 0, 0);
        z = __builtin_amdgcn_mfma_f32_16x16x32_f16(afrag[r*4+2], beff[2].h, z, 0, 0, 0);
        z = __builtin_amdgcn_mfma_f32_16x16x32_f16(afrag[r*4+3], beff[3].h, z, 0, 0, 0);
        acc[r] = z;
    }
    float mx = 0.f;
    #pragma unroll
    for (int r = 0; r < 8; ++r) {
        #pragma unroll
        for (int i = 0; i < 4; ++i) mx = fmaxf(mx, acc[r][i]);
    }
    mx = fmaxf(mx, __shfl_xor(mx, 16, 64));
    mx = fmaxf(mx, __shfl_xor(mx, 32, 64));
    const int eb = (__float_as_int(mx) >> 23) & 255;
    const float sig = __int_as_float((253 - eb) << 23);
    const bool act = (k <= lenc);
    #pragma unroll
    for (int q = 0; q < 4; ++q) {
        const int n0 = pk16(acc[2*q][0]*sig,   acc[2*q][1]*sig);
        const int n1 = pk16(acc[2*q][2]*sig,   acc[2*q][3]*sig);
        const int n2 = pk16(acc[2*q+1][0]*sig, acc[2*q+1][1]*sig);
        const int n3 = pk16(acc[2*q+1][2]*sig, acc[2*q+1][3]*sig);
        bf[q].u[0] = act ? n0 : bf[q].u[0];
        bf[q].u[1] = act ? n1 : bf[q].u[1];
        bf[q].u[2] = act ? n2 : bf[q].u[2];
        bf[q].u[3] = act ? n3 : bf[q].u[3];
    }
    Ecum += act ? (eb - 126) : 0;
}

// ---------------------------------------------------------------------------
// Worker: 576 blocks x 128 threads (2 waves). bid: chain b = bid/9,
// group wg = bid%9; column c covers segment s_raw = 16*wg + c + 1 (1..144,
// clamped to 129 for addressing). Wave 0 = FWD(s), wave 1 = BWD(s) — both
// consume rows lo..hi, staged ONCE in shared LDS (waves split the staging).
// FWD u-recursion (R27-proven): step1 = no-multiply, step k>=2 uses
// eeL[k-2] (rows lo..hi-1), store multiplies eeL[lenc-1] (row hi).
// BWD (R27-proven): step k uses eeL[max(lenc-k,0)] (rows hi..lo).
// ---------------------------------------------------------------------------
__global__ __launch_bounds__(128, 1)
void crf_worker_kernel(const float* __restrict__ emissions,
                       const int4* __restrict__ aF,
                       const int4* __restrict__ aB,
                       const int* __restrict__ token_sizes,
                       const float* __restrict__ head,
                       const float* __restrict__ last,
                       float* __restrict__ wsA, float* __restrict__ wsB,
                       float* __restrict__ wsLa, float* __restrict__ wsLb) {
    const int tid = threadIdx.x;
    const int L = tid & 63;
    const int w01 = tid >> 6;            // 0 = fwd wave, 1 = bwd wave
    const int c = L & 15;
    const int g = L >> 4;
    const int bid = blockIdx.x;
    const int b = bid / BPC;
    const int wg = bid % BPC;

    __shared__ __align__(16) int4 eeL[8][4][64];   // rows lo..hi (shared), 32 KB

    const int s_raw = 16 * wg + c + 1;   // 1..144
    const int s = min(s_raw, SEG);       // clamp for addressing
    const bool isFwd = (w01 == 0);
    const bool valid = isFwd ? (s_raw <= NFW) : (s_raw >= 2 && s_raw <= SEG);

    const float* em_c = emissions + (size_t)b * Tq * Nq;
    const int tsz = token_sizes[b];
    const int nst = tsz - 1;
    const int base = nst / SEG;          // 3..7
    const int rem = nst % SEG;
    const int lo = 1 + (s - 1) * base + min(s - 1, rem);
    const int lenc = base + ((s <= rem) ? 1 : 0);   // 3..8
    const int hi = lo + lenc - 1;
    const int kmax = base + 1;           // 4..8, uniform per block

    // A fragments: 32 coalesced b128 loads (permuted layout from prep)
    half8 afrag[32];
    {
        const int4* asrc = isFwd ? aF : aB;
        #pragma unroll
        for (int kf = 0; kf < 32; ++kf) {
            BU t; t.v = asrc[kf * 64 + L];
            afrag[kf] = t.h;
        }
    }

    // ---- cooperative staging: wave w01 stages slots 4*w01 .. 4*w01+3 ----
    #pragma unroll
    for (int ii = 0; ii < 4; ++ii) {
        const int i = 4 * w01 + ii;
        const int row = min(lo + i, hi);
        const float* bp = em_c + (size_t)row * Nq;
        #pragma unroll
        for (int q = 0; q < 4; ++q) eeL[i][q][L] = packRowQ(bp, q, g);
    }

    // init vector in PERMUTED B layout (true init at chain ends, ones-probe)
    BU bf[4];
    float M0c;
    {
        float a0[32];
        float mx = -1e30f;
        #pragma unroll
        for (int q = 0; q < 4; ++q) {
            #pragma unroll
            for (int j2 = 0; j2 < 8; ++j2) {
                const int m = MMAP(q, g, j2);
                float v;
                if (isFwd) v = (s_raw == 1)   ? (head[m] + em_c[m]) : 0.f;
                else       v = (s_raw == SEG) ? last[m]             : 0.f;
                a0[q*8+j2] = v;
                mx = fmaxf(mx, v);
            }
        }
        mx = fmaxf(mx, __shfl_xor(mx, 16, 64));
        mx = fmaxf(mx, __shfl_xor(mx, 32, 64));
        M0c = mx;
        #pragma unroll
        for (int q = 0; q < 4; ++q) {
            #pragma unroll
            for (int p = 0; p < 4; ++p)
                bf[q].u[p] = pk16(__expf(a0[q*8+2*p]   - M0c),
                                  __expf(a0[q*8+2*p+1] - M0c));
        }
    }

    __syncthreads();   // staging complete (both waves)

    int Ecum = 0;
    if (isFwd) {
        pstep(1, lenc, 0,              false, L, eeL, afrag, bf, Ecum);
        pstep(2, lenc, 0,              true,  L, eeL, afrag, bf, Ecum);
        pstep(3, lenc, 1,              true,  L, eeL, afrag, bf, Ecum);
        pstep(4, lenc, 2,              true,  L, eeL, afrag, bf, Ecum);
        if (kmax >= 5) pstep(5, lenc, 3, true, L, eeL, afrag, bf, Ecum);
        if (kmax >= 6) pstep(6, lenc, 4, true, L, eeL, afrag, bf, Ecum);
        if (kmax >= 7) pstep(7, lenc, 5, true, L, eeL, afrag, bf, Ecum);
        if (kmax >= 8) pstep(8, lenc, 6, true, L, eeL, afrag, bf, Ecum);
    } else {
        pstep(1, lenc, max(lenc - 1, 0), true, L, eeL, afrag, bf, Ecum);
        pstep(2, lenc, max(lenc - 2, 0), true, L, eeL, afrag, bf, Ecum);
        pstep(3, lenc, max(lenc - 3, 0), true, L, eeL, afrag, bf, Ecum);
        pstep(4, lenc, max(lenc - 4, 0), true, L, eeL, afrag, bf, Ecum);
        if (kmax >= 5) pstep(5, lenc, max(lenc - 5, 0), true, L, eeL, afrag, bf, Ecum);
        if (kmax >= 6) pstep(6, lenc, max(lenc - 6, 0), true, L, eeL, afrag, bf, Ecum);
        if (kmax >= 7) pstep(7, lenc, max(lenc - 7, 0), true, L, eeL, afrag, bf, Ecum);
        if (kmax >= 8) pstep(8, lenc, max(lenc - 8, 0), true, L, eeL, afrag, bf, Ecum);
    }

    // store (natural state order, f32) + ledger.  FWD multiplies ee_hi here.
    if (valid) {
        float* dst = isFwd ? (wsA + ((size_t)(s - 1) * Bq + b) * Nq)
                           : (wsB + ((size_t)(s - 2) * Bq + b) * Nq);
        BU eeHi[4];
        if (isFwd) {
            #pragma unroll
            for (int q = 0; q < 4; ++q) eeHi[q].v = eeL[lenc - 1][q][L];
        }
        #pragma unroll
        for (int q = 0; q < 4; ++q) {
            f32x4 v0, v1;
            #pragma unroll
            for (int t = 0; t < 4; ++t) {
                const float m0 = isFwd ? (float)eeHi[q].h[t]     : 1.0f;
                const float m1 = isFwd ? (float)eeHi[q].h[4 + t] : 1.0f;
                v0[t] = (float)bf[q].h[t]     * m0;
                v1[t] = (float)bf[q].h[4 + t] * m1;
            }
            *(f32x4*)(dst + 32*q + 4*g)      = v0;
            *(f32x4*)(dst + 32*q + 16 + 4*g) = v1;
        }
        if (g == 0) {
            const float led = M0c + (float)Ecum * LN2;
            if (isFwd) wsLa[(s - 1) * Bq + b] = led;
            else       wsLb[(s - 2) * Bq + b] = led;
        }
    }
}

// ---------------------------------------------------------------------------
// Combine + score (R27-proven). Blocks 0..63: rank-1 telescope (16 waves,
// LDS partials, no atomics). Blocks 64..127: gold-path score (1024 threads).
// ---------------------------------------------------------------------------
__global__ __launch_bounds__(1024)
void crf_combine_kernel(const float* __restrict__ wsA,
                        const float* __restrict__ wsB,
                        const float* __restrict__ wsLa,
                        const float* __restrict__ wsLb,
                        const float* __restrict__ emissions,
                        const int* __restrict__ token_sizes,
                        const int* __restrict__ targets,
                        const float* __restrict__ transitions,
                        const float* __restrict__ head,
                        const float* __restrict__ last,
                        float* __restrict__ out) {
    const int bid = blockIdx.x;
    const int tid = threadIdx.x;
    __shared__ float part[16];

    if (bid < Bq) {
        const int chain = bid;
        const int wq = tid >> 6;                   // wave 0..15
        const int l = tid & 63;
        float tot = 0.f;
        #pragma unroll
        for (int rep = 0; rep < 8; ++rep) {        // j = wq + 16*rep, 128 total
            const int j = wq + 16 * rep;
            const float* bb = wsB + ((size_t)j * Bq + chain) * Nq;
            const float* aa = wsA + ((size_t)j * Bq + chain) * Nq;
            float z = bb[l] * aa[l] + bb[l + 64] * aa[l + 64];
            float cc = bb[l] + bb[l + 64];
            #pragma unroll
            for (int off = 32; off >= 1; off >>= 1) {
                z  += __shfl_xor(z, off, 64);
                cc += __shfl_xor(cc, off, 64);
            }
            float term = __logf(z) + wsLa[j * Bq + chain];
            term += (j == NFW - 1) ? wsLb[(NBW - 1) * Bq + chain] : -__logf(cc);
            tot += term;
        }
        if (l == 0) part[wq] = tot;
        __syncthreads();
        if (tid == 0) {
            float tz = 0.f;
            #pragma unroll
            for (int i = 0; i < 16; ++i) tz += part[i];
            out[chain] = tz;
        }
        return;
    }
    // ---------------- score path ----------------
    {
        const int b = bid - Bq;
        const int tsz = token_sizes[b];
        const int* tg = targets + b * Tq;
        const float* emc = emissions + (size_t)b * Tq * Nq;
        float sc = 0.f;
        if (tid < tsz) {
            const int cur = tg[tid];
            sc = emc[(size_t)tid * Nq + cur];
            if (tid >= 1) sc += transitions[tg[tid - 1] * Nq + cur];
        }
        #pragma unroll
        for (int off = 32; off >= 1; off >>= 1)
            sc += __shfl_xor(sc, off, 64);
        if ((tid & 63) == 0) part[tid >> 6] = sc;
        __syncthreads();
        if (tid == 0) {
            float tot = 0.f;
            #pragma unroll
            for (int i = 0; i < 16; ++i) tot += part[i];
            out[Bq + b] = tot + head[tg[0]] + last[tg[tsz - 1]];
        }
    }
}

extern "C" void kernel_launch(void* const* d_in, const int* in_sizes, int n_in,
                              void* d_out, int out_size, void* d_ws, size_t ws_size,
                              hipStream_t stream) {
    const float* emissions   = (const float*)d_in[0];
    const int*   token_sizes = (const int*)d_in[1];
    const int*   targets     = (const int*)d_in[2];
    const float* transitions = (const float*)d_in[3];  // (1,1,128,128)
    const float* head        = (const float*)d_in[4];  // (1,1,128)
    const float* last        = (const float*)d_in[5];  // (1,1,128)
    float* out = (float*)d_out;                        // (2,64,1) flat

    char* wp = (char*)d_ws;
    int4* aF = (int4*)wp;                                wp += 32 * 64 * 16;              // 32 KB
    int4* aB = (int4*)wp;                                wp += 32 * 64 * 16;              // 32 KB
    float* wsA  = (float*)wp;                            wp += (size_t)NFW * Bq * Nq * 4; // 4 MB
    float* wsB  = (float*)wp;                            wp += (size_t)NBW * Bq * Nq * 4; // 4 MB
    float* wsLa = (float*)wp;                            wp += NFW * Bq * 4;
    float* wsLb = (float*)wp;                            wp += NBW * Bq * 4;

    crf_prep_kernel<<<16, 256, 0, stream>>>(transitions, aF, aB);
    crf_worker_kernel<<<Bq * BPC, 128, 0, stream>>>(
        emissions, aF, aB, token_sizes, head, last,
        wsA, wsB, wsLa, wsLb);
    crf_combine_kernel<<<2 * Bq, 1024, 0, stream>>>(
        wsA, wsB, wsLa, wsLb,
        emissions, token_sizes, targets, transitions, head, last, out);
}